// Round 15
// baseline (167.970 us; speedup 1.0000x reference)
//
#include <hip/hip_runtime.h>
#include <hip/hip_fp16.h>

#define BB   8
#define CIN  64
#define COUT 64
#define HH   128
#define WW   128
#define HWSZ (HH * WW)

typedef _Float16 f16x8 __attribute__((ext_vector_type(8)));
typedef _Float16 h2v   __attribute__((ext_vector_type(2)));
typedef float    f32x4 __attribute__((ext_vector_type(4)));

__device__ __forceinline__ unsigned short f2h_u(float f) {
    __half h = __float2half(f);
    return __half_as_ushort(h);
}
__device__ __forceinline__ float h2f_u(unsigned short u) {
    _Float16 f = *(_Float16*)&u;
    return (float)f;
}
// pack two floats as f16 pair (lo, hi)
__device__ __forceinline__ unsigned pk2h(float lo, float hi) {
    return (unsigned)f2h_u(lo) | ((unsigned)f2h_u(hi) << 16);
}
__device__ __forceinline__ h2v dupL(unsigned u) { h2v v = *(h2v*)&u; return (h2v){v[0], v[0]}; }
__device__ __forceinline__ h2v dupH(unsigned u) { h2v v = *(h2v*)&u; return (h2v){v[1], v[1]}; }

// packed bilinear combine of one 2-channel f16 pair across 4 corners:
// pure v_pk_mul/v_pk_fma_f16, no unpacking.
__device__ __forceinline__ unsigned comb2h(unsigned a, unsigned b, unsigned c, unsigned d,
                                           h2v W0, h2v W1, h2v W2, h2v W3) {
    h2v A = *(h2v*)&a, B = *(h2v*)&b, C = *(h2v*)&c, D = *(h2v*)&d;
    h2v r = A * W0;
    r += B * W1;
    r += C * W2;
    r += D * W3;
    return *(unsigned*)&r;
}

// ---------------------------------------------------------------------------
// k_wt: weight repack (f16) + sums zero. 64 blocks x 256 thr (~2 us).
//   wdT[k][co][c] f16 (36864), wofT[k][o][c] f16 padded to 32 o (18432).
// ---------------------------------------------------------------------------
__global__ __launch_bounds__(256) void k_wt(const float* __restrict__ wd,
                                            const float* __restrict__ wof,
                                            unsigned short* __restrict__ wdT,
                                            unsigned short* __restrict__ wofT,
                                            float4* __restrict__ sums4)
{
    const int t = threadIdx.x;
    const int id = blockIdx.x;
    if (id == 0) sums4[t] = make_float4(0.f, 0.f, 0.f, 0.f);  // 4096 B
    int base = id * 256 + t;
#pragma unroll
    for (int j = 0; j < 4; ++j) {
        int idx = base + j * 16384;
        if (idx < 36864) {
            int k = idx >> 12, rem = idx & 4095, co = rem >> 6, c = rem & 63;
            wdT[idx] = f2h_u(wd[(co * 64 + c) * 9 + k]);
        } else if (idx < 55296) {
            int jj = idx - 36864;
            int k = jj >> 11, rem = jj & 2047, o = rem >> 6, c = rem & 63;
            wofT[jj] = (o < 27) ? f2h_u(wof[(o * 64 + c) * 9 + k]) : 0;
        }
    }
}

// ---------------------------------------------------------------------------
// k_fused: offset-conv + DCN gather in ONE kernel, staging DIRECTLY from x
//   (NCHW fp32) with on-the-fly fp32->f16 transpose -- k_tr and the xT
//   buffer are eliminated. 256 blocks x 512 threads (8 waves, 4 output
//   rows, 8-row staged window h0-2..h0+5 per 32-ch half).
//   Phase A: stage half0/half1 from x, accumulate 27-ch offset conv (MFMA
//     f16; column boundary = clamp+zero B-fragment, row boundary =
//     wave-uniform tap skip), finalize bias+sigmoid -> om_sh (LDS).
//   Phase B: verified gather/meta/MFMA loop (r13/r14), offsets from om_sh.
//     Gather half1 first (tile holds it), restage half0, gather. Rare
//     out-of-window fallback reads x fp32 strided (bit31 flag; d0 holds
//     the pixel index in that case, tile short-index otherwise).
//   LDS 101,376 B -> 1 block/CU (occupancy-insensitive per r11-r13).
//   Epilogue: f16 y store + fused stats. XCD-swizzled. No VGPR cap (r11).
// ---------------------------------------------------------------------------
__global__ __launch_bounds__(512) void k_fused(
    const float* __restrict__ x, const unsigned short* __restrict__ wdT,
    const unsigned short* __restrict__ wofT, const float* __restrict__ bof,
    const float* __restrict__ bd, unsigned short* __restrict__ yh,
    float2* __restrict__ sums)
{
    __shared__ unsigned short tile_sh[8 * 128 * 32];   // 65,536 B
    __shared__ unsigned short om_sh[27 * 512];         // 27,648 B
    __shared__ uint4          meta_sh[8][64];          //  8,192 B (epi: red scratch)

    const int t = threadIdx.x;
    const int lane = t & 63, wv = t >> 6;              // wv in 0..7
    const int q = lane >> 4, l15 = lane & 15;
    const int b = blockIdx.x & 7;                      // XCD = b
    const int pblk = (blockIdx.x >> 3) * 512;          // 4 output rows
    const int p = pblk + t;                            // owner's point
    const int h = p >> 7, w = p & 127;
    const int h0 = pblk >> 7;                          // first output row (mult of 4)
    const float* xF = x + (size_t)b * 64 * HWSZ;       // batch base (NCHW fp32)
    const int gch = q * 8;                             // gather chunk (shorts)

    // conv wave geometry: wave covers row h0+(wv>>1), column half (wv&1)*64
    const int hrow = h0 + (wv >> 1);
    const int c0 = (wv & 1) * 64;

// stage 8 rows x 128 px x 32 ch of half HF from x (fp32 NCHW), converting
// to f16 and transposing to [row][px][ch] in tile_sh. Job = (row, ch-pair,
// 4-px group): 2 coalesced float4 loads -> 4 packed b32 LDS writes.
// Lane map c2 = t&15 spreads writes over 16 banks (4-way, cheap).
#define STAGE_X(HF) { \
    const float* xp_ = xF + (size_t)((HF) * 32) * HWSZ; \
    _Pragma("unroll") \
    for (int i_ = 0; i_ < 8; ++i_) { \
        int idx_ = i_ * 512 + t;            /* 0..4095 jobs */ \
        int s_  = idx_ >> 9;                /* row 0..7 */ \
        int c2_ = idx_ & 15;                /* ch-pair 0..15 */ \
        int g_  = (idx_ >> 4) & 31;         /* 4-px group 0..31 */ \
        int y_ = min(max(h0 - 2 + s_, 0), HH - 1); \
        const float* pa_ = xp_ + (size_t)(2 * c2_) * HWSZ + y_ * WW + g_ * 4; \
        float4 v0_ = *(const float4*)pa_; \
        float4 v1_ = *(const float4*)(pa_ + HWSZ); \
        unsigned short* wp_ = &tile_sh[s_ * 4096 + g_ * 128 + 2 * c2_]; \
        *(unsigned*)(wp_ +  0) = pk2h(v0_.x, v1_.x); \
        *(unsigned*)(wp_ + 32) = pk2h(v0_.y, v1_.y); \
        *(unsigned*)(wp_ + 64) = pk2h(v0_.z, v1_.z); \
        *(unsigned*)(wp_ + 96) = pk2h(v0_.w, v1_.w); \
    } }

    // ---- Phase A: offset conv ----
    f32x4 aoff[2][4];
#pragma unroll
    for (int mt = 0; mt < 2; ++mt)
#pragma unroll
        for (int nt = 0; nt < 4; ++nt) aoff[mt][nt] = (f32x4){0.f, 0.f, 0.f, 0.f};

    for (int hf = 0; hf < 2; ++hf) {
        __syncthreads();                               // tile free to overwrite
        STAGE_X(hf);
        __syncthreads();                               // tile ready
#pragma unroll
        for (int k = 0; k < 9; ++k) {
            const int ky = k / 3 - 1, kx = k % 3 - 1;
            if ((unsigned)(hrow + ky) < (unsigned)HH) {
                const int trow = hrow + ky - (h0 - 2);     // 1..6, in window
                const unsigned short* wk = wofT + k * 2048;
                f16x8 af[2];
#pragma unroll
                for (int mt = 0; mt < 2; ++mt)
                    af[mt] = *(const f16x8*)(wk + (mt * 16 + l15) * 64 + hf * 32 + q * 8);
                f16x8 bfr[4];
#pragma unroll
                for (int nt = 0; nt < 4; ++nt) {
                    int tc = c0 + nt * 16 + l15 + kx;
                    int tcc = min(max(tc, 0), WW - 1);
                    f16x8 bv = *(const f16x8*)&tile_sh[trow * 4096 + tcc * 32 + q * 8];
                    if ((unsigned)tc >= (unsigned)WW)
                        bv = (f16x8){(_Float16)0, (_Float16)0, (_Float16)0, (_Float16)0,
                                     (_Float16)0, (_Float16)0, (_Float16)0, (_Float16)0};
                    bfr[nt] = bv;
                }
#pragma unroll
                for (int mt = 0; mt < 2; ++mt)
#pragma unroll
                    for (int nt = 0; nt < 4; ++nt)
                        aoff[mt][nt] = __builtin_amdgcn_mfma_f32_16x16x32_f16(
                            af[mt], bfr[nt], aoff[mt][nt], 0, 0, 0);
            }
        }
    }
    // finalize om: bias, sigmoid(mask), f16 -> om_sh[o][point-in-block]
    {
        const int pw = (wv >> 1) * 128 + c0;
#pragma unroll
        for (int mt = 0; mt < 2; ++mt)
#pragma unroll
            for (int r = 0; r < 4; ++r) {
                int o = mt * 16 + q * 4 + r;
                if (o < 27) {
                    float bias = bof[o];
#pragma unroll
                    for (int nt = 0; nt < 4; ++nt) {
                        float v = aoff[mt][nt][r] + bias;
                        if (o >= 18) v = 1.f / (1.f + __expf(-v));
                        om_sh[o * 512 + pw + nt * 16 + l15] = f2h_u(v);
                    }
                }
            }
    }
    __syncthreads();                                   // om_sh ready

    // ---- Phase B: DCN gather (verified loop body; om from LDS) ----
    f32x4 acc[4][4];                                   // [mt][g]
#pragma unroll
    for (int mt = 0; mt < 4; ++mt)
#pragma unroll
        for (int g = 0; g < 4; ++g) acc[mt][g] = (f32x4){0.f, 0.f, 0.f, 0.f};

// fallback corner load: 8 strided fp32 from x, pack to f16x8 (rare)
#define FBLOAD(DST, pix_) { \
    const float* fp_ = xFq + (pix_); \
    uint4 R_; \
    R_.x = pk2h(fp_[0],        fp_[HWSZ]); \
    R_.y = pk2h(fp_[2 * HWSZ], fp_[3 * HWSZ]); \
    R_.z = pk2h(fp_[4 * HWSZ], fp_[5 * HWSZ]); \
    R_.w = pk2h(fp_[6 * HWSZ], fp_[7 * HWSZ]); \
    DST = R_; }

// unpack meta + load 4 corners (tile; or rare global fallback from x)
#define LOADG2(P, g) { \
    unsigned d0_ = M[g].x; \
    if (__builtin_expect((int)(d0_ >> 31), 0)) { \
        unsigned pix_ = d0_ & 0x000fffffu; \
        unsigned dx_  = (d0_ >> 24) & 1u; \
        unsigned dy_  = ((d0_ >> 25) & 1u) * WW; \
        FBLOAD(P[0], pix_); \
        FBLOAD(P[1], pix_ + dx_); \
        FBLOAD(P[2], pix_ + dy_); \
        FBLOAD(P[3], pix_ + dy_ + dx_); \
    } else { \
        unsigned b0_ = (d0_ & 0x000fffffu) + gch; \
        unsigned sx_ = (d0_ >> 19) & 32u;      /* bit24 -> 32  */ \
        unsigned sy_ = (d0_ >> 13) & 4096u;    /* bit25 -> 4096 */ \
        unsigned b1_ = b0_ + sx_; \
        P[0] = *(const uint4*)&tile_sh[b0_]; \
        P[1] = *(const uint4*)&tile_sh[b1_]; \
        P[2] = *(const uint4*)&tile_sh[b0_ + sy_]; \
        P[3] = *(const uint4*)&tile_sh[b1_ + sy_]; \
    } }

#define COMB2(DST, P, g) { \
    h2v W0_ = dupL(M[g].y), W2_ = dupH(M[g].y); \
    h2v W1_ = dupL(M[g].z), W3_ = dupH(M[g].z); \
    uint4 R_; \
    R_.x = comb2h(P[0].x, P[1].x, P[2].x, P[3].x, W0_, W1_, W2_, W3_); \
    R_.y = comb2h(P[0].y, P[1].y, P[2].y, P[3].y, W0_, W1_, W2_, W3_); \
    R_.z = comb2h(P[0].z, P[1].z, P[2].z, P[3].z, W0_, W1_, W2_, W3_); \
    R_.w = comb2h(P[0].w, P[1].w, P[2].w, P[3].w, W0_, W1_, W2_, W3_); \
    DST = *(f16x8*)&R_; }

    for (int pass = 0; pass < 2; ++pass) {
        const int hfg = 1 - pass;                      // half1 first (tile holds it)
        if (pass == 1) {
            __syncthreads();                           // tile free to overwrite
            STAGE_X(0);
            __syncthreads();                           // tile ready
        }
        const float* xFq = xF + (size_t)(hfg * 32 + q * 8) * HWSZ;

        float offy = h2f_u(om_sh[0 * 512 + t]);
        float offx = h2f_u(om_sh[1 * 512 + t]);
        float mk   = h2f_u(om_sh[18 * 512 + t]);

        for (int k = 0; k < 9; ++k) {
            // owner: bilinear corner setup for this lane's point
            float ys = (float)(h + (k / 3) - 1) + offy;
            float xs = (float)(w + (k % 3) - 1) + offx;
            float fy0 = floorf(ys), fx0 = floorf(xs);
            float wy1 = ys - fy0, wx1 = xs - fx0;
            float wy0 = 1.f - wy1, wx0 = 1.f - wx1;
            int y0 = (int)fy0, x0 = (int)fx0;
            int y1 = y0 + 1, x1 = x0 + 1;
            bool vy0 = (y0 >= 0) && (y0 < HH), vy1 = (y1 >= 0) && (y1 < HH);
            bool vx0 = (x0 >= 0) && (x0 < WW), vx1 = (x1 >= 0) && (x1 < WW);
            int y0c = min(max(y0, 0), HH - 1), y1c = min(max(y1, 0), HH - 1);
            int x0c = min(max(x0, 0), WW - 1), x1c = min(max(x1, 0), WW - 1);
            // in-tile iff clamped rows within staged window [h0-2, h0+5]
            bool ft = (y0c < h0 - 2) || (y1c > h0 + 5);
            unsigned d0;
            if (!ft) d0 = (unsigned)((y0c - h0 + 2) * 4096 + x0c * 32);
            else     d0 = 0x80000000u | (unsigned)(y0c * WW + x0c);
            if (x1c != x0c) d0 |= 0x01000000u;
            if (y1c != y0c) d0 |= 0x02000000u;
            float w00 = (vy0 && vx0) ? mk * wy0 * wx0 : 0.f;
            float w01 = (vy0 && vx1) ? mk * wy0 * wx1 : 0.f;
            float w10 = (vy1 && vx0) ? mk * wy1 * wx0 : 0.f;
            float w11 = (vy1 && vx1) ? mk * wy1 * wx1 : 0.f;
            meta_sh[wv][lane] = make_uint4(d0, pk2h(w00, w10), pk2h(w01, w11), 0u);
            int kn = (k < 8) ? k + 1 : 8;
            offy = h2f_u(om_sh[(2 * kn) * 512 + t]);
            offx = h2f_u(om_sh[(2 * kn + 1) * 512 + t]);
            mk   = h2f_u(om_sh[(18 + kn) * 512 + t]);
            __builtin_amdgcn_wave_barrier();

            // fetch packed meta for the points this gather lane serves
            uint4 M[4];
#pragma unroll
            for (int g = 0; g < 4; ++g)
                M[g] = meta_sh[wv][g * 16 + l15];

            // weight A-fragments for this tap/half (L1-resident)
            const unsigned short* wk = wdT + k * 4096;
            f16x8 af_[4];
#pragma unroll
            for (int mt = 0; mt < 4; ++mt)
                af_[mt] = *(const f16x8*)(wk + (mt * 16 + l15) * 64 + (hfg << 5) + q * 8);

            // gather + combine straight into B-fragments, distance-2 pipeline
            f16x8 bfr[4];
            uint4 pb[3][4];
            LOADG2(pb[0], 0);
            LOADG2(pb[1], 1);
#pragma unroll
            for (int g = 0; g < 4; ++g) {
                if (g + 2 < 4) LOADG2(pb[(g + 2) % 3], g + 2);
                COMB2(bfr[g], pb[g % 3], g);
            }

            // MFMA: this tap, this half (K=32)
#pragma unroll
            for (int mt = 0; mt < 4; ++mt)
#pragma unroll
                for (int g = 0; g < 4; ++g)
                    acc[mt][g] = __builtin_amdgcn_mfma_f32_16x16x32_f16(
                        af_[mt], bfr[g], acc[mt][g], 0, 0, 0);
        }
    }
#undef LOADG2
#undef FBLOAD
#undef COMB2
#undef STAGE_X

    // epilogue: bias add, f16 store to yh, per-(b,co) sum/sumsq partials.
    // Reduction scratch ALIASES meta_sh -> need all waves past main loop.
    __syncthreads();
    float* redS = (float*)&meta_sh[0][0];              // [8][64]
    float* redQ = redS + 512;                          // [8][64]
    const int p0 = pblk + wv * 64;
    unsigned short* yb = yh + (size_t)b * COUT * HWSZ;
#pragma unroll
    for (int mt = 0; mt < 4; ++mt)
#pragma unroll
        for (int r = 0; r < 4; ++r) {
            int co = mt * 16 + q * 4 + r;
            float bias = bd[co];
            float s = 0.f, qq = 0.f;
#pragma unroll
            for (int g = 0; g < 4; ++g) {
                float v = acc[mt][g][r] + bias;
                yb[(size_t)co * HWSZ + p0 + g * 16 + l15] = f2h_u(v);
                s += v; qq += v * v;
            }
#pragma unroll
            for (int m = 1; m < 16; m <<= 1) {
                s += __shfl_xor(s, m);
                qq += __shfl_xor(qq, m);
            }
            if (l15 == 0) { redS[wv * 64 + co] = s; redQ[wv * 64 + co] = qq; }
        }
    __syncthreads();
    if (t < 64) {
        float S = 0.f, Q = 0.f;
#pragma unroll
        for (int wvi = 0; wvi < 8; ++wvi) {
            S += redS[wvi * 64 + t];
            Q += redQ[wvi * 64 + t];
        }
        atomicAdd(&sums[b * 64 + t].x, S);
        atomicAdd(&sums[b * 64 + t].y, Q);
    }
}

// ---------------------------------------------------------------------------
// k_norm: read f16 yh, normalize + ReLU, write fp32 out. 8 f16/thread.
//         XCD-swizzled (b = id & 7).
// ---------------------------------------------------------------------------
__global__ __launch_bounds__(256) void k_norm(const unsigned short* __restrict__ yh,
                                              float* __restrict__ out,
                                              const float2* __restrict__ sums)
{
    const int id = blockIdx.x;
    const int b = id & 7;
    const int rest = id >> 3;            // 0..511
    const int co = rest >> 3;            // 0..63
    const int off = rest & 7;            // 0..7
    const int bco = b * 64 + co;
    float2 sq = sums[bco];
    float mu  = sq.x * (1.f / (float)HWSZ);
    float var = sq.y * (1.f / (float)HWSZ) - mu * mu;
    float rstd = rsqrtf(var + 1e-5f);
    const int base = (bco << 14) + off * 2048 + threadIdx.x * 8;
    uint4 v8 = *(const uint4*)(yh + base);
    float4 o0, o1;
    o0.x = fmaxf((h2f_u((unsigned short)(v8.x & 0xffffu)) - mu) * rstd, 0.f);
    o0.y = fmaxf((h2f_u((unsigned short)(v8.x >> 16))     - mu) * rstd, 0.f);
    o0.z = fmaxf((h2f_u((unsigned short)(v8.y & 0xffffu)) - mu) * rstd, 0.f);
    o0.w = fmaxf((h2f_u((unsigned short)(v8.y >> 16))     - mu) * rstd, 0.f);
    o1.x = fmaxf((h2f_u((unsigned short)(v8.z & 0xffffu)) - mu) * rstd, 0.f);
    o1.y = fmaxf((h2f_u((unsigned short)(v8.z >> 16))     - mu) * rstd, 0.f);
    o1.z = fmaxf((h2f_u((unsigned short)(v8.w & 0xffffu)) - mu) * rstd, 0.f);
    o1.w = fmaxf((h2f_u((unsigned short)(v8.w >> 16))     - mu) * rstd, 0.f);
    *(float4*)(out + base)     = o0;
    *(float4*)(out + base + 4) = o1;
}

extern "C" void kernel_launch(void* const* d_in, const int* in_sizes, int n_in,
                              void* d_out, int out_size, void* d_ws, size_t ws_size,
                              hipStream_t stream) {
    const float* x   = (const float*)d_in[0];
    const float* wof = (const float*)d_in[1];
    const float* bof = (const float*)d_in[2];
    const float* wd  = (const float*)d_in[3];
    const float* bd  = (const float*)d_in[4];
    float* out = (float*)d_out;

    char* ws = (char*)d_ws;
    unsigned short* yh   = (unsigned short*)ws;                  // 16,777,216 B
    unsigned short* wdT  = (unsigned short*)(ws + 16777216);     //     73,728 B
    unsigned short* wofT = (unsigned short*)(ws + 16850944);     //     36,864 B
    float2*         sums = (float2*)(ws + 16887808);             //      4,096 B

    k_wt    <<<64, 256, 0, stream>>>(wd, wof, wdT, wofT, (float4*)sums);
    k_fused <<<256, 512, 0, stream>>>(x, wdT, wofT, bof, bd, yh, sums);
    k_norm  <<<4096, 256, 0, stream>>>(yh, out, (const float2*)sums);
}

// Round 17
// 143.880 us; speedup vs baseline: 1.1674x; 1.1674x over previous
//
#include <hip/hip_runtime.h>
#include <hip/hip_fp16.h>

#define BB   8
#define CIN  64
#define COUT 64
#define HH   128
#define WW   128
#define HWSZ (HH * WW)

typedef _Float16 f16x8 __attribute__((ext_vector_type(8)));
typedef _Float16 h2v   __attribute__((ext_vector_type(2)));
typedef float    f32x4 __attribute__((ext_vector_type(4)));

__device__ __forceinline__ unsigned short f2h_u(float f) {
    __half h = __float2half(f);
    return __half_as_ushort(h);
}
__device__ __forceinline__ float h2f_u(unsigned short u) {
    _Float16 f = *(_Float16*)&u;
    return (float)f;
}
// pack two floats as f16 pair (lo, hi)
__device__ __forceinline__ unsigned pk2h(float lo, float hi) {
    return (unsigned)f2h_u(lo) | ((unsigned)f2h_u(hi) << 16);
}
__device__ __forceinline__ h2v dupL(unsigned u) { h2v v = *(h2v*)&u; return (h2v){v[0], v[0]}; }
__device__ __forceinline__ h2v dupH(unsigned u) { h2v v = *(h2v*)&u; return (h2v){v[1], v[1]}; }

// packed bilinear combine of one 2-channel f16 pair across 4 corners:
// pure v_pk_mul/v_pk_fma_f16, no unpacking.
__device__ __forceinline__ unsigned comb2h(unsigned a, unsigned b, unsigned c, unsigned d,
                                           h2v W0, h2v W1, h2v W2, h2v W3) {
    h2v A = *(h2v*)&a, B = *(h2v*)&b, C = *(h2v*)&c, D = *(h2v*)&d;
    h2v r = A * W0;
    r += B * W1;
    r += C * W2;
    r += D * W3;
    return *(unsigned*)&r;
}

// ---------------------------------------------------------------------------
// xT layout (half-planar): per batch b (2^20 shorts):
//   xT[b<<20 + half<<19 + pixel*32 + c]   half in {0,1}, c in [0,32)
// yh layout: f16 planes yh[b][64][HWSZ] (ushort) -- pre-norm DCN output.
// ---------------------------------------------------------------------------

// ---------------------------------------------------------------------------
// k_tr: x NCHW fp32 -> xT half-planar f16, XCD-swizzled (b = id & 7).
//       Blocks 512..575: weight repack (f16); block 512 also zeroes sums.
//   (r15 tried eliminating k_tr by staging from x in k_fused: bank
//   conflicts 5.5M->18M, +32 us. k_tr's conflict-engineered transpose +
//   f16-compressed re-reads are worth its ~10 us.)
// ---------------------------------------------------------------------------
__global__ __launch_bounds__(256) void k_tr(const float* __restrict__ x,
                                            const float* __restrict__ wd,
                                            const float* __restrict__ wof,
                                            unsigned short* __restrict__ xT,
                                            unsigned short* __restrict__ wdT,
                                            unsigned short* __restrict__ wofT,
                                            float4* __restrict__ sums4)
{
    const int t = threadIdx.x;
    const int id = blockIdx.x;
    if (id >= 512) {
        if (id == 512) sums4[t] = make_float4(0.f, 0.f, 0.f, 0.f);  // 4096 B
        int base = (id - 512) * 256 + t;
#pragma unroll
        for (int j = 0; j < 4; ++j) {
            int idx = base + j * 16384;
            if (idx < 36864) {
                int k = idx >> 12, rem = idx & 4095, co = rem >> 6, c = rem & 63;
                wdT[idx] = f2h_u(wd[(co * 64 + c) * 9 + k]);
            } else if (idx < 55296) {
                int jj = idx - 36864;
                int k = jj >> 11, rem = jj & 2047, o = rem >> 6, c = rem & 63;
                wofT[jj] = (o < 27) ? f2h_u(wof[(o * 64 + c) * 9 + k]) : 0;
            }
        }
        return;
    }
    __shared__ unsigned short tile[256 * 66];
    const int b = id & 7;                 // XCD = linear_id % 8 = b
    const int p0 = (id >> 3) * 256;
#pragma unroll
    for (int i = 0; i < 16; ++i) {
        int c = i * 4 + (t >> 6);
        int pl = (t & 63) * 4;
        float4 v = *(const float4*)(x + (((size_t)b * 64 + c) << 14) + p0 + pl);
        tile[(pl + 0) * 66 + c] = f2h_u(v.x);
        tile[(pl + 1) * 66 + c] = f2h_u(v.y);
        tile[(pl + 2) * 66 + c] = f2h_u(v.z);
        tile[(pl + 3) * 66 + c] = f2h_u(v.w);
    }
    __syncthreads();
#pragma unroll
    for (int i = 0; i < 8; ++i) {
        int idd = i * 256 + t;
        int pt = idd >> 3, ck = idd & 7;
        const unsigned* srcp = (const unsigned*)&tile[pt * 66 + ck * 8];
        uint4 r;
        r.x = srcp[0]; r.y = srcp[1]; r.z = srcp[2]; r.w = srcp[3];
        // half-planar: chunk ck holds channels ck*8.. -> half = ck>>2, word (ck&3)
        *(uint4*)(xT + ((size_t)b << 20) + ((size_t)(ck >> 2) << 19)
                     + (size_t)(p0 + pt) * 32 + (ck & 3) * 8) = r;
    }
}

// ---------------------------------------------------------------------------
// k_fused: offset-conv + DCN gather in ONE kernel. 256 blocks x 512 threads
//   (8 waves, 4 output rows, 8-row staged window h0-2..h0+5 per half).
//   Phase A: stage half0/half1, accumulate 27-ch offset conv (MFMA f16,
//     K=32/half/tap; column boundary handled by clamp+zero B-fragment, row
//     boundary by wave-uniform tap skip), finalize bias+sigmoid -> om_sh
//     (f16, 27x512, LDS -- no HBM round-trip, k_off eliminated).
//   Phase B: verified gather/meta/MFMA loop, offsets read from om_sh.
//     Gather half1 first (tile already holds it), restage half0, gather.
//   LDS 101,376 B -> 1 block/CU (8 waves; r11-13 showed occupancy-
//   insensitive 8<->16 waves). No VGPR cap (r11's cap spilled). Epilogue:
//   f16 y store + fused stats. XCD-swizzled.
// ---------------------------------------------------------------------------
__global__ __launch_bounds__(512) void k_fused(
    const unsigned short* __restrict__ xT, const unsigned short* __restrict__ wdT,
    const unsigned short* __restrict__ wofT, const float* __restrict__ bof,
    const float* __restrict__ bd, unsigned short* __restrict__ yh,
    float2* __restrict__ sums)
{
    __shared__ unsigned short tile_sh[8 * 128 * 32];   // 65,536 B
    __shared__ unsigned short om_sh[27 * 512];         // 27,648 B
    __shared__ uint4          meta_sh[8][64];          //  8,192 B (epi: red scratch)

    const int t = threadIdx.x;
    const int lane = t & 63, wv = t >> 6;              // wv in 0..7
    const int q = lane >> 4, l15 = lane & 15;
    const int b = blockIdx.x & 7;                      // XCD = b
    const int pblk = (blockIdx.x >> 3) * 512;          // 4 output rows
    const int p = pblk + t;                            // owner's point
    const int h = p >> 7, w = p & 127;
    const int h0 = pblk >> 7;                          // first output row (mult of 4)
    const unsigned short* xbS = xT + ((size_t)b << 20);
    const int gch = q * 8;                             // gather chunk (shorts)

    // conv wave geometry: wave covers row h0+(wv>>1), column half (wv&1)*64
    const int hrow = h0 + (wv >> 1);
    const int c0 = (wv & 1) * 64;

#define STAGE(HF) { \
    const unsigned short* xs_ = xbS + ((HF) << 19); \
    _Pragma("unroll") \
    for (int i_ = 0; i_ < 8; ++i_) { \
        int idx_ = i_ * 512 + t; \
        int s_ = idx_ >> 9, u_ = idx_ & 511; \
        int y_ = h0 - 2 + s_; \
        y_ = min(max(y_, 0), HH - 1); \
        uint4 v_ = *(const uint4*)(xs_ + (size_t)y_ * (WW * 32) + u_ * 8); \
        *(uint4*)&tile_sh[idx_ * 8] = v_; \
    } }

    // ---- Phase A: offset conv ----
    f32x4 aoff[2][4];
#pragma unroll
    for (int mt = 0; mt < 2; ++mt)
#pragma unroll
        for (int nt = 0; nt < 4; ++nt) aoff[mt][nt] = (f32x4){0.f, 0.f, 0.f, 0.f};

    for (int hf = 0; hf < 2; ++hf) {
        __syncthreads();                               // tile free to overwrite
        STAGE(hf);
        __syncthreads();                               // tile ready
#pragma unroll
        for (int k = 0; k < 9; ++k) {
            const int ky = k / 3 - 1, kx = k % 3 - 1;
            if ((unsigned)(hrow + ky) < (unsigned)HH) {
                const int trow = hrow + ky - (h0 - 2);     // 1..6, in window
                const unsigned short* wk = wofT + k * 2048;
                f16x8 af[2];
#pragma unroll
                for (int mt = 0; mt < 2; ++mt)
                    af[mt] = *(const f16x8*)(wk + (mt * 16 + l15) * 64 + hf * 32 + q * 8);
                f16x8 bfr[4];
#pragma unroll
                for (int nt = 0; nt < 4; ++nt) {
                    int tc = c0 + nt * 16 + l15 + kx;
                    int tcc = min(max(tc, 0), WW - 1);
                    f16x8 bv = *(const f16x8*)&tile_sh[trow * 4096 + tcc * 32 + q * 8];
                    if ((unsigned)tc >= (unsigned)WW)
                        bv = (f16x8){(_Float16)0, (_Float16)0, (_Float16)0, (_Float16)0,
                                     (_Float16)0, (_Float16)0, (_Float16)0, (_Float16)0};
                    bfr[nt] = bv;
                }
#pragma unroll
                for (int mt = 0; mt < 2; ++mt)
#pragma unroll
                    for (int nt = 0; nt < 4; ++nt)
                        aoff[mt][nt] = __builtin_amdgcn_mfma_f32_16x16x32_f16(
                            af[mt], bfr[nt], aoff[mt][nt], 0, 0, 0);
            }
        }
    }
    // finalize om: bias, sigmoid(mask), f16 -> om_sh[o][point-in-block]
    {
        const int pw = (wv >> 1) * 128 + c0;
#pragma unroll
        for (int mt = 0; mt < 2; ++mt)
#pragma unroll
            for (int r = 0; r < 4; ++r) {
                int o = mt * 16 + q * 4 + r;
                if (o < 27) {
                    float bias = bof[o];
#pragma unroll
                    for (int nt = 0; nt < 4; ++nt) {
                        float v = aoff[mt][nt][r] + bias;
                        if (o >= 18) v = 1.f / (1.f + __expf(-v));
                        om_sh[o * 512 + pw + nt * 16 + l15] = f2h_u(v);
                    }
                }
            }
    }
    __syncthreads();                                   // om_sh ready

    // ---- Phase B: DCN gather (verified loop body; om from LDS) ----
    f32x4 acc[4][4];                                   // [mt][g]
#pragma unroll
    for (int mt = 0; mt < 4; ++mt)
#pragma unroll
        for (int g = 0; g < 4; ++g) acc[mt][g] = (f32x4){0.f, 0.f, 0.f, 0.f};

// unpack meta + load 4 corners (tile or rare global fallback)
#define LOADG2(P, g) { \
    unsigned d0_ = M[g].x; \
    unsigned b0_ = (d0_ & 0x000fffffu) + gch; \
    unsigned sx_ = (d0_ >> 19) & 32u;      /* bit24 -> 32  */ \
    unsigned sy_ = (d0_ >> 13) & 4096u;    /* bit25 -> 4096 */ \
    unsigned b1_ = b0_ + sx_; \
    if (__builtin_expect((int)(d0_ >> 31), 0)) { \
        P[0] = *(const uint4*)(xbh + b0_); \
        P[1] = *(const uint4*)(xbh + b1_); \
        P[2] = *(const uint4*)(xbh + b0_ + sy_); \
        P[3] = *(const uint4*)(xbh + b1_ + sy_); \
    } else { \
        P[0] = *(const uint4*)&tile_sh[b0_]; \
        P[1] = *(const uint4*)&tile_sh[b1_]; \
        P[2] = *(const uint4*)&tile_sh[b0_ + sy_]; \
        P[3] = *(const uint4*)&tile_sh[b1_ + sy_]; \
    } }

#define COMB2(DST, P, g) { \
    h2v W0_ = dupL(M[g].y), W2_ = dupH(M[g].y); \
    h2v W1_ = dupL(M[g].z), W3_ = dupH(M[g].z); \
    uint4 R_; \
    R_.x = comb2h(P[0].x, P[1].x, P[2].x, P[3].x, W0_, W1_, W2_, W3_); \
    R_.y = comb2h(P[0].y, P[1].y, P[2].y, P[3].y, W0_, W1_, W2_, W3_); \
    R_.z = comb2h(P[0].z, P[1].z, P[2].z, P[3].z, W0_, W1_, W2_, W3_); \
    R_.w = comb2h(P[0].w, P[1].w, P[2].w, P[3].w, W0_, W1_, W2_, W3_); \
    DST = *(f16x8*)&R_; }

    for (int pass = 0; pass < 2; ++pass) {
        const int hfg = 1 - pass;                      // half1 first (tile holds it)
        if (pass == 1) {
            __syncthreads();                           // tile free to overwrite
            STAGE(0);
            __syncthreads();                           // tile ready
        }
        const unsigned short* xbh = xbS + (hfg << 19);

        float offy = h2f_u(om_sh[0 * 512 + t]);
        float offx = h2f_u(om_sh[1 * 512 + t]);
        float mk   = h2f_u(om_sh[18 * 512 + t]);

        for (int k = 0; k < 9; ++k) {
            // owner: bilinear corner setup for this lane's point
            float ys = (float)(h + (k / 3) - 1) + offy;
            float xs = (float)(w + (k % 3) - 1) + offx;
            float fy0 = floorf(ys), fx0 = floorf(xs);
            float wy1 = ys - fy0, wx1 = xs - fx0;
            float wy0 = 1.f - wy1, wx0 = 1.f - wx1;
            int y0 = (int)fy0, x0 = (int)fx0;
            int y1 = y0 + 1, x1 = x0 + 1;
            bool vy0 = (y0 >= 0) && (y0 < HH), vy1 = (y1 >= 0) && (y1 < HH);
            bool vx0 = (x0 >= 0) && (x0 < WW), vx1 = (x1 >= 0) && (x1 < WW);
            int y0c = min(max(y0, 0), HH - 1), y1c = min(max(y1, 0), HH - 1);
            int x0c = min(max(x0, 0), WW - 1), x1c = min(max(x1, 0), WW - 1);
            // in-tile iff clamped rows within staged window [h0-2, h0+5]
            bool ft = (y0c < h0 - 2) || (y1c > h0 + 5);
            unsigned d0;
            if (!ft) d0 = (unsigned)((y0c - h0 + 2) * 4096 + x0c * 32);
            else     d0 = 0x80000000u | (unsigned)((y0c * WW + x0c) * 32);
            if (x1c != x0c) d0 |= 0x01000000u;
            if (y1c != y0c) d0 |= 0x02000000u;
            float w00 = (vy0 && vx0) ? mk * wy0 * wx0 : 0.f;
            float w01 = (vy0 && vx1) ? mk * wy0 * wx1 : 0.f;
            float w10 = (vy1 && vx0) ? mk * wy1 * wx0 : 0.f;
            float w11 = (vy1 && vx1) ? mk * wy1 * wx1 : 0.f;
            meta_sh[wv][lane] = make_uint4(d0, pk2h(w00, w10), pk2h(w01, w11), 0u);
            int kn = (k < 8) ? k + 1 : 8;
            offy = h2f_u(om_sh[(2 * kn) * 512 + t]);
            offx = h2f_u(om_sh[(2 * kn + 1) * 512 + t]);
            mk   = h2f_u(om_sh[(18 + kn) * 512 + t]);
            __builtin_amdgcn_wave_barrier();

            // fetch packed meta for the points this gather lane serves
            uint4 M[4];
#pragma unroll
            for (int g = 0; g < 4; ++g)
                M[g] = meta_sh[wv][g * 16 + l15];

            // weight A-fragments for this tap/half (L1-resident)
            const unsigned short* wk = wdT + k * 4096;
            f16x8 af_[4];
#pragma unroll
            for (int mt = 0; mt < 4; ++mt)
                af_[mt] = *(const f16x8*)(wk + (mt * 16 + l15) * 64 + (hfg << 5) + q * 8);

            // gather + combine straight into B-fragments, distance-2 pipeline
            f16x8 bfr[4];
            uint4 pb[3][4];
            LOADG2(pb[0], 0);
            LOADG2(pb[1], 1);
#pragma unroll
            for (int g = 0; g < 4; ++g) {
                if (g + 2 < 4) LOADG2(pb[(g + 2) % 3], g + 2);
                COMB2(bfr[g], pb[g % 3], g);
            }

            // MFMA: this tap, this half (K=32)
#pragma unroll
            for (int mt = 0; mt < 4; ++mt)
#pragma unroll
                for (int g = 0; g < 4; ++g)
                    acc[mt][g] = __builtin_amdgcn_mfma_f32_16x16x32_f16(
                        af_[mt], bfr[g], acc[mt][g], 0, 0, 0);
        }
    }
#undef LOADG2
#undef COMB2
#undef STAGE

    // epilogue: bias add, f16 store to yh, per-(b,co) sum/sumsq partials.
    // Reduction scratch ALIASES meta_sh -> need all waves past main loop.
    __syncthreads();
    float* redS = (float*)&meta_sh[0][0];              // [8][64]
    float* redQ = redS + 512;                          // [8][64]
    const int p0 = pblk + wv * 64;
    unsigned short* yb = yh + (size_t)b * COUT * HWSZ;
#pragma unroll
    for (int mt = 0; mt < 4; ++mt)
#pragma unroll
        for (int r = 0; r < 4; ++r) {
            int co = mt * 16 + q * 4 + r;
            float bias = bd[co];
            float s = 0.f, qq = 0.f;
#pragma unroll
            for (int g = 0; g < 4; ++g) {
                float v = acc[mt][g][r] + bias;
                yb[(size_t)co * HWSZ + p0 + g * 16 + l15] = f2h_u(v);
                s += v; qq += v * v;
            }
#pragma unroll
            for (int m = 1; m < 16; m <<= 1) {
                s += __shfl_xor(s, m);
                qq += __shfl_xor(qq, m);
            }
            if (l15 == 0) { redS[wv * 64 + co] = s; redQ[wv * 64 + co] = qq; }
        }
    __syncthreads();
    if (t < 64) {
        float S = 0.f, Q = 0.f;
#pragma unroll
        for (int wvi = 0; wvi < 8; ++wvi) {
            S += redS[wvi * 64 + t];
            Q += redQ[wvi * 64 + t];
        }
        atomicAdd(&sums[b * 64 + t].x, S);
        atomicAdd(&sums[b * 64 + t].y, Q);
    }
}

// ---------------------------------------------------------------------------
// k_norm: read f16 yh, normalize + ReLU, write fp32 out. 8 f16/thread.
//         XCD-swizzled (b = id & 7).
// ---------------------------------------------------------------------------
__global__ __launch_bounds__(256) void k_norm(const unsigned short* __restrict__ yh,
                                              float* __restrict__ out,
                                              const float2* __restrict__ sums)
{
    const int id = blockIdx.x;
    const int b = id & 7;
    const int rest = id >> 3;            // 0..511
    const int co = rest >> 3;            // 0..63
    const int off = rest & 7;            // 0..7
    const int bco = b * 64 + co;
    float2 sq = sums[bco];
    float mu  = sq.x * (1.f / (float)HWSZ);
    float var = sq.y * (1.f / (float)HWSZ) - mu * mu;
    float rstd = rsqrtf(var + 1e-5f);
    const int base = (bco << 14) + off * 2048 + threadIdx.x * 8;
    uint4 v8 = *(const uint4*)(yh + base);
    float4 o0, o1;
    o0.x = fmaxf((h2f_u((unsigned short)(v8.x & 0xffffu)) - mu) * rstd, 0.f);
    o0.y = fmaxf((h2f_u((unsigned short)(v8.x >> 16))     - mu) * rstd, 0.f);
    o0.z = fmaxf((h2f_u((unsigned short)(v8.y & 0xffffu)) - mu) * rstd, 0.f);
    o0.w = fmaxf((h2f_u((unsigned short)(v8.y >> 16))     - mu) * rstd, 0.f);
    o1.x = fmaxf((h2f_u((unsigned short)(v8.z & 0xffffu)) - mu) * rstd, 0.f);
    o1.y = fmaxf((h2f_u((unsigned short)(v8.z >> 16))     - mu) * rstd, 0.f);
    o1.z = fmaxf((h2f_u((unsigned short)(v8.w & 0xffffu)) - mu) * rstd, 0.f);
    o1.w = fmaxf((h2f_u((unsigned short)(v8.w >> 16))     - mu) * rstd, 0.f);
    *(float4*)(out + base)     = o0;
    *(float4*)(out + base + 4) = o1;
}

extern "C" void kernel_launch(void* const* d_in, const int* in_sizes, int n_in,
                              void* d_out, int out_size, void* d_ws, size_t ws_size,
                              hipStream_t stream) {
    const float* x   = (const float*)d_in[0];
    const float* wof = (const float*)d_in[1];
    const float* bof = (const float*)d_in[2];
    const float* wd  = (const float*)d_in[3];
    const float* bd  = (const float*)d_in[4];
    float* out = (float*)d_out;

    char* ws = (char*)d_ws;
    unsigned short* xT   = (unsigned short*)ws;                  // 16,777,216 B
    unsigned short* yh   = (unsigned short*)(ws + 16777216);     // 16,777,216 B
    unsigned short* wdT  = (unsigned short*)(ws + 33554432);     //     73,728 B
    unsigned short* wofT = (unsigned short*)(ws + 33628160);     //     36,864 B
    float2*         sums = (float2*)(ws + 33665024);             //      4,096 B

    k_tr    <<<576, 256, 0, stream>>>(x, wd, wof, xT, wdT, wofT, (float4*)sums);
    k_fused <<<256, 512, 0, stream>>>(xT, wdT, wofT, bof, bd, yh, sums);
    k_norm  <<<4096, 256, 0, stream>>>(yh, out, (const float2*)sums);
}

// Round 18
// 143.335 us; speedup vs baseline: 1.1719x; 1.0038x over previous
//
#include <hip/hip_runtime.h>
#include <hip/hip_fp16.h>

#define BB   8
#define CIN  64
#define COUT 64
#define HH   128
#define WW   128
#define HWSZ (HH * WW)

typedef _Float16 f16x8 __attribute__((ext_vector_type(8)));
typedef _Float16 h2v   __attribute__((ext_vector_type(2)));
typedef float    f32x4 __attribute__((ext_vector_type(4)));

__device__ __forceinline__ unsigned short f2h_u(float f) {
    __half h = __float2half(f);
    return __half_as_ushort(h);
}
__device__ __forceinline__ float h2f_u(unsigned short u) {
    _Float16 f = *(_Float16*)&u;
    return (float)f;
}
// pack two floats as f16 pair (lo, hi)
__device__ __forceinline__ unsigned pk2h(float lo, float hi) {
    return (unsigned)f2h_u(lo) | ((unsigned)f2h_u(hi) << 16);
}
__device__ __forceinline__ h2v dupL(unsigned u) { h2v v = *(h2v*)&u; return (h2v){v[0], v[0]}; }
__device__ __forceinline__ h2v dupH(unsigned u) { h2v v = *(h2v*)&u; return (h2v){v[1], v[1]}; }

// packed bilinear combine of one 2-channel f16 pair across 4 corners:
// pure v_pk_mul/v_pk_fma_f16, no unpacking.
__device__ __forceinline__ unsigned comb2h(unsigned a, unsigned b, unsigned c, unsigned d,
                                           h2v W0, h2v W1, h2v W2, h2v W3) {
    h2v A = *(h2v*)&a, B = *(h2v*)&b, C = *(h2v*)&c, D = *(h2v*)&d;
    h2v r = A * W0;
    r += B * W1;
    r += C * W2;
    r += D * W3;
    return *(unsigned*)&r;
}

// ---------------------------------------------------------------------------
// xT layout (half-planar): per batch b (2^20 shorts):
//   xT[b<<20 + half<<19 + pixel*32 + c]   half in {0,1}, c in [0,32)
// yh layout: f16 planes yh[b][64][HWSZ] (ushort) -- pre-norm DCN output.
// ---------------------------------------------------------------------------

// ---------------------------------------------------------------------------
// k_tr: x NCHW fp32 -> xT half-planar f16, XCD-swizzled (b = id & 7).
//       Blocks 512..575: weight repack (f16); block 512 also zeroes sums.
//   (r15 tried eliminating k_tr by staging from x in k_fused: bank
//   conflicts 5.5M->18M, +32 us. k_tr's conflict-engineered transpose +
//   f16-compressed re-reads are worth its ~10 us.)
// ---------------------------------------------------------------------------
__global__ __launch_bounds__(256) void k_tr(const float* __restrict__ x,
                                            const float* __restrict__ wd,
                                            const float* __restrict__ wof,
                                            unsigned short* __restrict__ xT,
                                            unsigned short* __restrict__ wdT,
                                            unsigned short* __restrict__ wofT,
                                            float4* __restrict__ sums4)
{
    const int t = threadIdx.x;
    const int id = blockIdx.x;
    if (id >= 512) {
        if (id == 512) sums4[t] = make_float4(0.f, 0.f, 0.f, 0.f);  // 4096 B
        int base = (id - 512) * 256 + t;
#pragma unroll
        for (int j = 0; j < 4; ++j) {
            int idx = base + j * 16384;
            if (idx < 36864) {
                int k = idx >> 12, rem = idx & 4095, co = rem >> 6, c = rem & 63;
                wdT[idx] = f2h_u(wd[(co * 64 + c) * 9 + k]);
            } else if (idx < 55296) {
                int jj = idx - 36864;
                int k = jj >> 11, rem = jj & 2047, o = rem >> 6, c = rem & 63;
                wofT[jj] = (o < 27) ? f2h_u(wof[(o * 64 + c) * 9 + k]) : 0;
            }
        }
        return;
    }
    __shared__ unsigned short tile[256 * 66];
    const int b = id & 7;                 // XCD = linear_id % 8 = b
    const int p0 = (id >> 3) * 256;
#pragma unroll
    for (int i = 0; i < 16; ++i) {
        int c = i * 4 + (t >> 6);
        int pl = (t & 63) * 4;
        float4 v = *(const float4*)(x + (((size_t)b * 64 + c) << 14) + p0 + pl);
        tile[(pl + 0) * 66 + c] = f2h_u(v.x);
        tile[(pl + 1) * 66 + c] = f2h_u(v.y);
        tile[(pl + 2) * 66 + c] = f2h_u(v.z);
        tile[(pl + 3) * 66 + c] = f2h_u(v.w);
    }
    __syncthreads();
#pragma unroll
    for (int i = 0; i < 8; ++i) {
        int idd = i * 256 + t;
        int pt = idd >> 3, ck = idd & 7;
        const unsigned* srcp = (const unsigned*)&tile[pt * 66 + ck * 8];
        uint4 r;
        r.x = srcp[0]; r.y = srcp[1]; r.z = srcp[2]; r.w = srcp[3];
        // half-planar: chunk ck holds channels ck*8.. -> half = ck>>2, word (ck&3)
        *(uint4*)(xT + ((size_t)b << 20) + ((size_t)(ck >> 2) << 19)
                     + (size_t)(p0 + pt) * 32 + (ck & 3) * 8) = r;
    }
}

// ---------------------------------------------------------------------------
// k_fused: offset-conv + DCN gather in ONE kernel. 256 blocks x 512 threads
//   (8 waves, 4 output rows, 8-row staged window h0-2..h0+5 per half).
//   Phase A: stage half0/half1, accumulate 27-ch offset conv (MFMA f16,
//     K=32/half/tap), finalize bias+sigmoid -> om_sh.
//   om_sh layout (NEW): [tap][point][4] = {offy, offx, mk, pad} f16, so
//     Phase B reads ONE aligned b64 per tap instead of 3 scalar u16 reads
//     (-36 LDS ops/thread; reads are 8B-stride = free 2-way banking).
//   Phase B: verified gather/meta/MFMA loop, offsets from om_sh.
//     Gather half1 first (tile already holds it), restage half0, gather.
//   LDS 110,592 B -> 1 block/CU (occupancy-insensitive per r11-r13).
//   No VGPR cap (r11's cap spilled). Epilogue: f16 y store + fused stats.
//   XCD-swizzled.
// ---------------------------------------------------------------------------
__global__ __launch_bounds__(512) void k_fused(
    const unsigned short* __restrict__ xT, const unsigned short* __restrict__ wdT,
    const unsigned short* __restrict__ wofT, const float* __restrict__ bof,
    const float* __restrict__ bd, unsigned short* __restrict__ yh,
    float2* __restrict__ sums)
{
    __shared__ unsigned short tile_sh[8 * 128 * 32];   // 65,536 B
    __shared__ unsigned short om_sh[9 * 512 * 4];      // 36,864 B [tap][pt][4]
    __shared__ uint4          meta_sh[8][64];          //  8,192 B (epi: red scratch)

    const int t = threadIdx.x;
    const int lane = t & 63, wv = t >> 6;              // wv in 0..7
    const int q = lane >> 4, l15 = lane & 15;
    const int b = blockIdx.x & 7;                      // XCD = b
    const int pblk = (blockIdx.x >> 3) * 512;          // 4 output rows
    const int p = pblk + t;                            // owner's point
    const int h = p >> 7, w = p & 127;
    const int h0 = pblk >> 7;                          // first output row (mult of 4)
    const unsigned short* xbS = xT + ((size_t)b << 20);
    const int gch = q * 8;                             // gather chunk (shorts)

    // conv wave geometry: wave covers row h0+(wv>>1), column half (wv&1)*64
    const int hrow = h0 + (wv >> 1);
    const int c0 = (wv & 1) * 64;

#define STAGE(HF) { \
    const unsigned short* xs_ = xbS + ((HF) << 19); \
    _Pragma("unroll") \
    for (int i_ = 0; i_ < 8; ++i_) { \
        int idx_ = i_ * 512 + t; \
        int s_ = idx_ >> 9, u_ = idx_ & 511; \
        int y_ = h0 - 2 + s_; \
        y_ = min(max(y_, 0), HH - 1); \
        uint4 v_ = *(const uint4*)(xs_ + (size_t)y_ * (WW * 32) + u_ * 8); \
        *(uint4*)&tile_sh[idx_ * 8] = v_; \
    } }

    // ---- Phase A: offset conv ----
    f32x4 aoff[2][4];
#pragma unroll
    for (int mt = 0; mt < 2; ++mt)
#pragma unroll
        for (int nt = 0; nt < 4; ++nt) aoff[mt][nt] = (f32x4){0.f, 0.f, 0.f, 0.f};

    for (int hf = 0; hf < 2; ++hf) {
        __syncthreads();                               // tile free to overwrite
        STAGE(hf);
        __syncthreads();                               // tile ready
#pragma unroll
        for (int k = 0; k < 9; ++k) {
            const int ky = k / 3 - 1, kx = k % 3 - 1;
            if ((unsigned)(hrow + ky) < (unsigned)HH) {
                const int trow = hrow + ky - (h0 - 2);     // 1..6, in window
                const unsigned short* wk = wofT + k * 2048;
                f16x8 af[2];
#pragma unroll
                for (int mt = 0; mt < 2; ++mt)
                    af[mt] = *(const f16x8*)(wk + (mt * 16 + l15) * 64 + hf * 32 + q * 8);
                f16x8 bfr[4];
#pragma unroll
                for (int nt = 0; nt < 4; ++nt) {
                    int tc = c0 + nt * 16 + l15 + kx;
                    int tcc = min(max(tc, 0), WW - 1);
                    f16x8 bv = *(const f16x8*)&tile_sh[trow * 4096 + tcc * 32 + q * 8];
                    if ((unsigned)tc >= (unsigned)WW)
                        bv = (f16x8){(_Float16)0, (_Float16)0, (_Float16)0, (_Float16)0,
                                     (_Float16)0, (_Float16)0, (_Float16)0, (_Float16)0};
                    bfr[nt] = bv;
                }
#pragma unroll
                for (int mt = 0; mt < 2; ++mt)
#pragma unroll
                    for (int nt = 0; nt < 4; ++nt)
                        aoff[mt][nt] = __builtin_amdgcn_mfma_f32_16x16x32_f16(
                            af[mt], bfr[nt], aoff[mt][nt], 0, 0, 0);
            }
        }
    }
    // finalize om: bias, sigmoid(mask), f16 -> om_sh[tap][point][slot]
    {
        const int pw = (wv >> 1) * 128 + c0;
#pragma unroll
        for (int mt = 0; mt < 2; ++mt)
#pragma unroll
            for (int r = 0; r < 4; ++r) {
                int o = mt * 16 + q * 4 + r;
                if (o < 27) {
                    float bias = bof[o];
                    int tap  = (o < 18) ? (o >> 1) : (o - 18);
                    int slot = (o < 18) ? (o & 1) : 2;
#pragma unroll
                    for (int nt = 0; nt < 4; ++nt) {
                        float v = aoff[mt][nt][r] + bias;
                        if (o >= 18) v = 1.f / (1.f + __expf(-v));
                        om_sh[tap * 2048 + (pw + nt * 16 + l15) * 4 + slot] = f2h_u(v);
                    }
                }
            }
    }
    __syncthreads();                                   // om_sh ready

    // ---- Phase B: DCN gather (verified loop body; om from LDS, b64/tap) ----
    f32x4 acc[4][4];                                   // [mt][g]
#pragma unroll
    for (int mt = 0; mt < 4; ++mt)
#pragma unroll
        for (int g = 0; g < 4; ++g) acc[mt][g] = (f32x4){0.f, 0.f, 0.f, 0.f};

// unpack meta + load 4 corners (tile or rare global fallback)
#define LOADG2(P, g) { \
    unsigned d0_ = M[g].x; \
    unsigned b0_ = (d0_ & 0x000fffffu) + gch; \
    unsigned sx_ = (d0_ >> 19) & 32u;      /* bit24 -> 32  */ \
    unsigned sy_ = (d0_ >> 13) & 4096u;    /* bit25 -> 4096 */ \
    unsigned b1_ = b0_ + sx_; \
    if (__builtin_expect((int)(d0_ >> 31), 0)) { \
        P[0] = *(const uint4*)(xbh + b0_); \
        P[1] = *(const uint4*)(xbh + b1_); \
        P[2] = *(const uint4*)(xbh + b0_ + sy_); \
        P[3] = *(const uint4*)(xbh + b1_ + sy_); \
    } else { \
        P[0] = *(const uint4*)&tile_sh[b0_]; \
        P[1] = *(const uint4*)&tile_sh[b1_]; \
        P[2] = *(const uint4*)&tile_sh[b0_ + sy_]; \
        P[3] = *(const uint4*)&tile_sh[b1_ + sy_]; \
    } }

#define COMB2(DST, P, g) { \
    h2v W0_ = dupL(M[g].y), W2_ = dupH(M[g].y); \
    h2v W1_ = dupL(M[g].z), W3_ = dupH(M[g].z); \
    uint4 R_; \
    R_.x = comb2h(P[0].x, P[1].x, P[2].x, P[3].x, W0_, W1_, W2_, W3_); \
    R_.y = comb2h(P[0].y, P[1].y, P[2].y, P[3].y, W0_, W1_, W2_, W3_); \
    R_.z = comb2h(P[0].z, P[1].z, P[2].z, P[3].z, W0_, W1_, W2_, W3_); \
    R_.w = comb2h(P[0].w, P[1].w, P[2].w, P[3].w, W0_, W1_, W2_, W3_); \
    DST = *(f16x8*)&R_; }

    for (int pass = 0; pass < 2; ++pass) {
        const int hfg = 1 - pass;                      // half1 first (tile holds it)
        if (pass == 1) {
            __syncthreads();                           // tile free to overwrite
            STAGE(0);
            __syncthreads();                           // tile ready
        }
        const unsigned short* xbh = xbS + (hfg << 19);

        uint2 om2 = *(const uint2*)&om_sh[t * 4];      // tap 0
        float offy = h2f_u((unsigned short)(om2.x & 0xffffu));
        float offx = h2f_u((unsigned short)(om2.x >> 16));
        float mk   = h2f_u((unsigned short)(om2.y & 0xffffu));

        for (int k = 0; k < 9; ++k) {
            // owner: bilinear corner setup for this lane's point
            float ys = (float)(h + (k / 3) - 1) + offy;
            float xs = (float)(w + (k % 3) - 1) + offx;
            float fy0 = floorf(ys), fx0 = floorf(xs);
            float wy1 = ys - fy0, wx1 = xs - fx0;
            float wy0 = 1.f - wy1, wx0 = 1.f - wx1;
            int y0 = (int)fy0, x0 = (int)fx0;
            int y1 = y0 + 1, x1 = x0 + 1;
            bool vy0 = (y0 >= 0) && (y0 < HH), vy1 = (y1 >= 0) && (y1 < HH);
            bool vx0 = (x0 >= 0) && (x0 < WW), vx1 = (x1 >= 0) && (x1 < WW);
            int y0c = min(max(y0, 0), HH - 1), y1c = min(max(y1, 0), HH - 1);
            int x0c = min(max(x0, 0), WW - 1), x1c = min(max(x1, 0), WW - 1);
            // in-tile iff clamped rows within staged window [h0-2, h0+5]
            bool ft = (y0c < h0 - 2) || (y1c > h0 + 5);
            unsigned d0;
            if (!ft) d0 = (unsigned)((y0c - h0 + 2) * 4096 + x0c * 32);
            else     d0 = 0x80000000u | (unsigned)((y0c * WW + x0c) * 32);
            if (x1c != x0c) d0 |= 0x01000000u;
            if (y1c != y0c) d0 |= 0x02000000u;
            float w00 = (vy0 && vx0) ? mk * wy0 * wx0 : 0.f;
            float w01 = (vy0 && vx1) ? mk * wy0 * wx1 : 0.f;
            float w10 = (vy1 && vx0) ? mk * wy1 * wx0 : 0.f;
            float w11 = (vy1 && vx1) ? mk * wy1 * wx1 : 0.f;
            meta_sh[wv][lane] = make_uint4(d0, pk2h(w00, w10), pk2h(w01, w11), 0u);
            int kn = (k < 8) ? k + 1 : 8;
            uint2 om2n = *(const uint2*)&om_sh[kn * 2048 + t * 4];
            offy = h2f_u((unsigned short)(om2n.x & 0xffffu));
            offx = h2f_u((unsigned short)(om2n.x >> 16));
            mk   = h2f_u((unsigned short)(om2n.y & 0xffffu));
            __builtin_amdgcn_wave_barrier();

            // fetch packed meta for the points this gather lane serves
            uint4 M[4];
#pragma unroll
            for (int g = 0; g < 4; ++g)
                M[g] = meta_sh[wv][g * 16 + l15];

            // weight A-fragments for this tap/half (L1-resident)
            const unsigned short* wk = wdT + k * 4096;
            f16x8 af_[4];
#pragma unroll
            for (int mt = 0; mt < 4; ++mt)
                af_[mt] = *(const f16x8*)(wk + (mt * 16 + l15) * 64 + (hfg << 5) + q * 8);

            // gather + combine straight into B-fragments, distance-2 pipeline
            f16x8 bfr[4];
            uint4 pb[3][4];
            LOADG2(pb[0], 0);
            LOADG2(pb[1], 1);
#pragma unroll
            for (int g = 0; g < 4; ++g) {
                if (g + 2 < 4) LOADG2(pb[(g + 2) % 3], g + 2);
                COMB2(bfr[g], pb[g % 3], g);
            }

            // MFMA: this tap, this half (K=32)
#pragma unroll
            for (int mt = 0; mt < 4; ++mt)
#pragma unroll
                for (int g = 0; g < 4; ++g)
                    acc[mt][g] = __builtin_amdgcn_mfma_f32_16x16x32_f16(
                        af_[mt], bfr[g], acc[mt][g], 0, 0, 0);
        }
    }
#undef LOADG2
#undef COMB2
#undef STAGE

    // epilogue: bias add, f16 store to yh, per-(b,co) sum/sumsq partials.
    // Reduction scratch ALIASES meta_sh -> need all waves past main loop.
    __syncthreads();
    float* redS = (float*)&meta_sh[0][0];              // [8][64]
    float* redQ = redS + 512;                          // [8][64]
    const int p0 = pblk + wv * 64;
    unsigned short* yb = yh + (size_t)b * COUT * HWSZ;
#pragma unroll
    for (int mt = 0; mt < 4; ++mt)
#pragma unroll
        for (int r = 0; r < 4; ++r) {
            int co = mt * 16 + q * 4 + r;
            float bias = bd[co];
            float s = 0.f, qq = 0.f;
#pragma unroll
            for (int g = 0; g < 4; ++g) {
                float v = acc[mt][g][r] + bias;
                yb[(size_t)co * HWSZ + p0 + g * 16 + l15] = f2h_u(v);
                s += v; qq += v * v;
            }
#pragma unroll
            for (int m = 1; m < 16; m <<= 1) {
                s += __shfl_xor(s, m);
                qq += __shfl_xor(qq, m);
            }
            if (l15 == 0) { redS[wv * 64 + co] = s; redQ[wv * 64 + co] = qq; }
        }
    __syncthreads();
    if (t < 64) {
        float S = 0.f, Q = 0.f;
#pragma unroll
        for (int wvi = 0; wvi < 8; ++wvi) {
            S += redS[wvi * 64 + t];
            Q += redQ[wvi * 64 + t];
        }
        atomicAdd(&sums[b * 64 + t].x, S);
        atomicAdd(&sums[b * 64 + t].y, Q);
    }
}

// ---------------------------------------------------------------------------
// k_norm: read f16 yh, normalize + ReLU, write fp32 out. 8 f16/thread.
//         XCD-swizzled (b = id & 7).
// ---------------------------------------------------------------------------
__global__ __launch_bounds__(256) void k_norm(const unsigned short* __restrict__ yh,
                                              float* __restrict__ out,
                                              const float2* __restrict__ sums)
{
    const int id = blockIdx.x;
    const int b = id & 7;
    const int rest = id >> 3;            // 0..511
    const int co = rest >> 3;            // 0..63
    const int off = rest & 7;            // 0..7
    const int bco = b * 64 + co;
    float2 sq = sums[bco];
    float mu  = sq.x * (1.f / (float)HWSZ);
    float var = sq.y * (1.f / (float)HWSZ) - mu * mu;
    float rstd = rsqrtf(var + 1e-5f);
    const int base = (bco << 14) + off * 2048 + threadIdx.x * 8;
    uint4 v8 = *(const uint4*)(yh + base);
    float4 o0, o1;
    o0.x = fmaxf((h2f_u((unsigned short)(v8.x & 0xffffu)) - mu) * rstd, 0.f);
    o0.y = fmaxf((h2f_u((unsigned short)(v8.x >> 16))     - mu) * rstd, 0.f);
    o0.z = fmaxf((h2f_u((unsigned short)(v8.y & 0xffffu)) - mu) * rstd, 0.f);
    o0.w = fmaxf((h2f_u((unsigned short)(v8.y >> 16))     - mu) * rstd, 0.f);
    o1.x = fmaxf((h2f_u((unsigned short)(v8.z & 0xffffu)) - mu) * rstd, 0.f);
    o1.y = fmaxf((h2f_u((unsigned short)(v8.z >> 16))     - mu) * rstd, 0.f);
    o1.z = fmaxf((h2f_u((unsigned short)(v8.w & 0xffffu)) - mu) * rstd, 0.f);
    o1.w = fmaxf((h2f_u((unsigned short)(v8.w >> 16))     - mu) * rstd, 0.f);
    *(float4*)(out + base)     = o0;
    *(float4*)(out + base + 4) = o1;
}

extern "C" void kernel_launch(void* const* d_in, const int* in_sizes, int n_in,
                              void* d_out, int out_size, void* d_ws, size_t ws_size,
                              hipStream_t stream) {
    const float* x   = (const float*)d_in[0];
    const float* wof = (const float*)d_in[1];
    const float* bof = (const float*)d_in[2];
    const float* wd  = (const float*)d_in[3];
    const float* bd  = (const float*)d_in[4];
    float* out = (float*)d_out;

    char* ws = (char*)d_ws;
    unsigned short* xT   = (unsigned short*)ws;                  // 16,777,216 B
    unsigned short* yh   = (unsigned short*)(ws + 16777216);     // 16,777,216 B
    unsigned short* wdT  = (unsigned short*)(ws + 33554432);     //     73,728 B
    unsigned short* wofT = (unsigned short*)(ws + 33628160);     //     36,864 B
    float2*         sums = (float2*)(ws + 33665024);             //      4,096 B

    k_tr    <<<576, 256, 0, stream>>>(x, wd, wof, xT, wdT, wofT, (float4*)sums);
    k_fused <<<256, 512, 0, stream>>>(xT, wdT, wofT, bof, bd, yh, sums);
    k_norm  <<<4096, 256, 0, stream>>>(yh, out, (const float2*)sums);
}